// Round 5
// baseline (729.531 us; speedup 1.0000x reference)
//
#include <hip/hip_runtime.h>
#include <hip/hip_bf16.h>
#include <math.h>

// ---------------- problem constants ----------------
#define L_SEQ   4096
#define D_MODEL 2048
#define NQ      16
#define NKV     8
#define HD      128
#define CSTR    3072                   // combined QK row stride (NQ*HD + NKV*HD)
#define SCALING 0.08838834764831845f   // 128^-0.5
#define LOG2E   1.4426950408889634f
#define K_SEL   1024                   // L * 0.25

typedef __attribute__((ext_vector_type(8))) short bf16x8;
typedef __attribute__((ext_vector_type(4))) float f32x4;

__device__ __forceinline__ unsigned short f2bf(float f) {
  union { float f; unsigned u; } v; v.f = f;
  unsigned r = v.u + 0x7fffu + ((v.u >> 16) & 1u);   // RNE
  return (unsigned short)(r >> 16);
}
__device__ __forceinline__ unsigned pk2(float a, float b) {
  return (__float_as_uint(b) & 0xffff0000u) | (__float_as_uint(a) >> 16);
}
__device__ __forceinline__ float bf2f(unsigned short b) {
  union { unsigned u; float f; } v; v.u = ((unsigned)b) << 16;
  return v.f;
}

typedef __attribute__((address_space(3))) unsigned int lds_u32;
typedef const __attribute__((address_space(1))) unsigned int glob_u32;
__device__ __forceinline__ void gl2lds16(const unsigned short* g, unsigned short* l) {
  __builtin_amdgcn_global_load_lds((glob_u32*)g, (lds_u32*)l, 16, 0, 0);
}

// ============================================================
// Kernel 1: Wt[3072][2048] bf16 = transpose([wq | wk]), k-contiguous rows.
// ============================================================
__global__ __launch_bounds__(256) void prep_w(
    const float* __restrict__ wq, const float* __restrict__ wk,
    unsigned short* __restrict__ Wt) {
  __shared__ __align__(16) unsigned short T[64][80];
  const int tid = threadIdx.x;
  const int nt = blockIdx.x;      // 48 n-tiles
  const int kt = blockIdx.y;      // 32 k-tiles
  const float* src; int srcN, n0;
  if (nt < 32) { src = wq; srcN = 2048; n0 = nt * 64; }
  else         { src = wk; srcN = 1024; n0 = (nt - 32) * 64; }
  const int k0 = kt * 64;
#pragma unroll
  for (int p = 0; p < 4; ++p) {
    const int idx = p * 256 + tid;
    const int row = idx >> 4;
    const int c4 = (idx & 15) * 4;
    float4 v = *(const float4*)(src + (size_t)(k0 + row) * srcN + n0 + c4);
    T[c4 + 0][row] = f2bf(v.x); T[c4 + 1][row] = f2bf(v.y);
    T[c4 + 2][row] = f2bf(v.z); T[c4 + 3][row] = f2bf(v.w);
  }
  __syncthreads();
#pragma unroll
  for (int p = 0; p < 2; ++p) {
    const int c = p * 256 + tid;
    const int n = c >> 3, k8 = (c & 7) * 8;
    *(uint4*)(Wt + (size_t)(nt * 64 + n) * D_MODEL + k0 + k8) = *(const uint4*)(&T[n][k8]);
  }
}

// ============================================================
// Kernel 1b: A_bf16[4096][2048] = gather(table, ids), pk2-truncated
// (bit-identical to the old in-gemm conversion).
// ============================================================
__global__ __launch_bounds__(256) void prep_a(
    const int* __restrict__ ids, const float* __restrict__ table,
    unsigned short* __restrict__ A) {
  const int row = blockIdx.x;
  const float* src = table + (size_t)ids[row] * D_MODEL;
  const int c = threadIdx.x * 8;
  const float4 f0 = *(const float4*)(src + c);
  const float4 f1 = *(const float4*)(src + c + 4);
  uint4 u;
  u.x = pk2(f0.x, f0.y); u.y = pk2(f0.z, f0.w);
  u.z = pk2(f1.x, f1.y); u.w = pk2(f1.z, f1.w);
  *(uint4*)(A + (size_t)row * D_MODEL + c) = u;
}

// ============================================================
// Kernel 2: C[4096][3072] = A_bf16 @ [wq|wk]^T, MFMA bf16.
// Both operands staged via global_load_lds (16B); XOR chunk swizzle
// (chunk ^= (row>>1)&3, source-side) makes ds_read_b128 frag reads
// fully bank-spread (old layout was 8-way conflicted).
// ============================================================
__global__ __launch_bounds__(256) void gemm_qk(
    const unsigned short* __restrict__ A,
    const unsigned short* __restrict__ Wt, unsigned short* __restrict__ C) {
  __shared__ __align__(16) unsigned short As[128 * 32];
  __shared__ __align__(16) unsigned short Bs[128 * 32];
  const int tid = threadIdx.x;
  const int w = tid >> 6, lane = tid & 63;
  const int quad = lane >> 4, lr = lane & 15;
  const int m0 = blockIdx.y * 128, n0 = blockIdx.x * 128;
  const int wm = (w >> 1) * 64, wn = (w & 1) * 64;

  // staging: lane covers row (lane>>2), source chunk (lane&3)^((lane>>3)&3)
  const int srw = lane >> 2;
  const int schk = ((lane & 3) ^ ((lane >> 3) & 3)) * 8;
  const unsigned short* aptr0 = A + (size_t)(m0 + w * 16 + srw) * D_MODEL + schk;
  const unsigned short* aptr1 = aptr0 + (size_t)64 * D_MODEL;
  const unsigned short* bptr0 = Wt + (size_t)(n0 + w * 16 + srw) * D_MODEL + schk;
  const unsigned short* bptr1 = bptr0 + (size_t)64 * D_MODEL;
  unsigned short* asl0 = &As[(w * 16) * 32];
  unsigned short* asl1 = &As[(64 + w * 16) * 32];
  unsigned short* bsl0 = &Bs[(w * 16) * 32];
  unsigned short* bsl1 = &Bs[(64 + w * 16) * 32];

  // read-side swizzle selector: (row>>1)&3 == (lr>>1)&3 for our rows
  const int rsw = ((lr >> 1) & 3);

  f32x4 acc[4][4];
#pragma unroll
  for (int i = 0; i < 4; ++i)
#pragma unroll
    for (int j = 0; j < 4; ++j) acc[i][j] = (f32x4){0.f, 0.f, 0.f, 0.f};

  for (int k0 = 0; k0 < D_MODEL; k0 += 32) {
    __syncthreads();
    gl2lds16(aptr0 + k0, asl0);
    gl2lds16(aptr1 + k0, asl1);
    gl2lds16(bptr0 + k0, bsl0);
    gl2lds16(bptr1 + k0, bsl1);
    __syncthreads();
    bf16x8 af[4], bfr[4];
#pragma unroll
    for (int mt = 0; mt < 4; ++mt)
      af[mt] = *(const bf16x8*)&As[(wm + mt * 16 + lr) * 32 + (quad ^ rsw) * 8];
#pragma unroll
    for (int nt = 0; nt < 4; ++nt)
      bfr[nt] = *(const bf16x8*)&Bs[(wn + nt * 16 + lr) * 32 + (quad ^ rsw) * 8];
#pragma unroll
    for (int mt = 0; mt < 4; ++mt)
#pragma unroll
      for (int nt = 0; nt < 4; ++nt)
        acc[mt][nt] = __builtin_amdgcn_mfma_f32_16x16x32_bf16(af[mt], bfr[nt], acc[mt][nt], 0, 0, 0);
  }
#pragma unroll
  for (int mt = 0; mt < 4; ++mt) {
    const int row = m0 + wm + mt * 16 + quad * 4;
#pragma unroll
    for (int nt = 0; nt < 4; ++nt) {
      const int col = n0 + wn + nt * 16 + lr;
#pragma unroll
      for (int r = 0; r < 4; ++r)
        C[(size_t)(row + r) * CSTR + col] = f2bf(acc[mt][nt][r]);
    }
  }
}

// ============================================================
// Kernel 3a: RoPE cos/sin table tab[4096][64] (constants only).
// ============================================================
__global__ __launch_bounds__(256) void rope_tab(float2* __restrict__ tab) {
  const int g = blockIdx.x * blockDim.x + threadIdx.x;   // 4096*64
  const int t = g & 63;
  const int i = g >> 6;
  const float invf = exp2f((float)t * (-13.287712379549449f / 64.0f));
  const float ang = (float)i * invf;
  tab[g] = make_float2(cosf(ang), sinf(ang));
}

// ============================================================
// Kernel 3b: RoPE in place on combined C[4096][3072], table-driven.
// ============================================================
__global__ __launch_bounds__(256) void rope_all(
    unsigned short* __restrict__ C, const float2* __restrict__ tab) {
  const int g = blockIdx.x * blockDim.x + threadIdx.x;   // L*24*16 threads
  const int t4 = (g & 15) * 4;
  const int hi = g >> 4;
  const int h = hi % 24;
  const int i = hi / 24;
  const size_t base = (size_t)i * CSTR + h * HD + t4;
  ushort4 a = *(const ushort4*)(C + base);
  ushort4 b = *(const ushort4*)(C + base + 64);
  const float2 cs0 = tab[i * 64 + t4 + 0];
  const float2 cs1 = tab[i * 64 + t4 + 1];
  const float2 cs2 = tab[i * 64 + t4 + 2];
  const float2 cs3 = tab[i * 64 + t4 + 3];
  const float a0 = bf2f(a.x), a1 = bf2f(a.y), a2 = bf2f(a.z), a3 = bf2f(a.w);
  const float b0 = bf2f(b.x), b1 = bf2f(b.y), b2 = bf2f(b.z), b3 = bf2f(b.w);
  ushort4 ra, rb;
  ra.x = f2bf(a0 * cs0.x - b0 * cs0.y); rb.x = f2bf(b0 * cs0.x + a0 * cs0.y);
  ra.y = f2bf(a1 * cs1.x - b1 * cs1.y); rb.y = f2bf(b1 * cs1.x + a1 * cs1.y);
  ra.z = f2bf(a2 * cs2.x - b2 * cs2.y); rb.z = f2bf(b2 * cs2.x + a2 * cs2.y);
  ra.w = f2bf(a3 * cs3.x - b3 * cs3.y); rb.w = f2bf(b3 * cs3.x + a3 * cs3.y);
  *(ushort4*)(C + base) = ra;
  *(ushort4*)(C + base + 64) = rb;
}

// ------------------------------------------------------------
// K-tile staging: 64x128 bf16, linear LDS [64][128], XOR-swizzled SOURCE
// (16B chunk index ^= row&7).  global_load_lds: uniform LDS base + lane*16.
// ------------------------------------------------------------
__device__ __forceinline__ void stage_k(
    const unsigned short* __restrict__ kb_lane,   // per-lane pre-swizzled base
    unsigned short* buf, int j0, int w) {
#pragma unroll
  for (int p = 0; p < 4; ++p)
    gl2lds16(kb_lane + (size_t)(j0 + p * 16) * CSTR, &buf[(p * 16 + w * 4) * 128]);
}

// ============================================================
// Kernel 4: fused attention importance. One block per (q-row-block, kvh);
// pass 1 accumulates row denominators fully in registers (shfl-reduce),
// pass 2 reuses resident Q frags + l2r and accumulates column sums in an
// LDS buffer, flushed once per block. Heavy blocks dispatched first.
// ============================================================
__global__ __launch_bounds__(256) void attn_fused(
    const unsigned short* __restrict__ Qb,  // [L][CSTR], q heads at col 0
    const unsigned short* __restrict__ Kb,  // = Qb + 2048
    float* __restrict__ imp) {
  __shared__ __align__(16) unsigned short Ks[2][64 * 128];
  __shared__ float colacc[L_SEQ];
  const int tid = threadIdx.x;
  const int w = tid >> 6, lane = tid & 63;
  const int quad = lane >> 4, lr = lane & 15;
  const int kvh = blockIdx.y;
  const int bx = 63 - (int)blockIdx.x;      // heavy-first dispatch
  const int q0 = bx * 64;
  const int nt = bx + 1;                    // j-tiles owned by this block
  const int ncol = nt * 64;

  const int srow = w * 4 + (lane >> 4);
  const int scol = (lane & 15) ^ (srow & 7);
  const unsigned short* kb_lane = Kb + (size_t)srow * CSTR + kvh * HD + scol * 8;

  int coff[4];
#pragma unroll
  for (int m = 0; m < 4; ++m) coff[m] = (((m * 4 + quad) ^ (lr & 7)) * 8);

  bf16x8 aq[2][4];
  const size_t rowb = (size_t)(q0 + w * 16 + lr) * CSTR;
#pragma unroll
  for (int hh = 0; hh < 2; ++hh)
#pragma unroll
    for (int m = 0; m < 4; ++m)
      aq[hh][m] = *(const bf16x8*)(Qb + rowb + (2 * kvh + hh) * HD + m * 32 + quad * 8);

  for (int c = tid; c < ncol; c += 256) colacc[c] = 0.0f;

  // ---------------- pass 1: row sums (in registers) ----------------
  float zp[2][4] = {};
  stage_k(kb_lane, Ks[0], 0, w);
  __syncthreads();
  int cur = 0;
  for (int t = 0; t < nt; ++t) {
    if (t + 1 < nt) stage_k(kb_lane, Ks[cur ^ 1], (t + 1) * 64, w);
    const unsigned short* kbuf = Ks[cur];
    const bool diag = (t == bx);
    const int nsub = diag ? (w + 1) : 4;
    for (int sub = 0; sub < nsub; ++sub) {
      bf16x8 bfr[4];
#pragma unroll
      for (int m = 0; m < 4; ++m)
        bfr[m] = *(const bf16x8*)&kbuf[(sub * 16 + lr) * 128 + coff[m]];
      const bool masked = diag && (sub == w);
#pragma unroll
      for (int hh = 0; hh < 2; ++hh) {
        f32x4 acc = {0.f, 0.f, 0.f, 0.f};
#pragma unroll
        for (int m = 0; m < 4; ++m)
          acc = __builtin_amdgcn_mfma_f32_16x16x32_bf16(aq[hh][m], bfr[m], acc, 0, 0, 0);
#pragma unroll
        for (int r = 0; r < 4; ++r) {
          float e = exp2f(acc[r] * (SCALING * LOG2E));
          if (masked && lr > quad * 4 + r) e = 0.0f;
          zp[hh][r] += e;
        }
      }
    }
    __syncthreads();
    cur ^= 1;
  }

  // reduce row sums across the 16 col-lanes; every lane gets the total
  float l2r[2][4];
#pragma unroll
  for (int hh = 0; hh < 2; ++hh)
#pragma unroll
    for (int r = 0; r < 4; ++r) {
      float z = zp[hh][r];
      z += __shfl_xor(z, 1); z += __shfl_xor(z, 2);
      z += __shfl_xor(z, 4); z += __shfl_xor(z, 8);
      l2r[hh][r] = -__log2f(z);
    }

  // ---------------- pass 2: column sums ----------------
  stage_k(kb_lane, Ks[0], 0, w);
  __syncthreads();
  cur = 0;
  for (int t = 0; t < nt; ++t) {
    if (t + 1 < nt) stage_k(kb_lane, Ks[cur ^ 1], (t + 1) * 64, w);
    const unsigned short* kbuf = Ks[cur];
    const bool diag = (t == bx);
    const int nsub = diag ? (w + 1) : 4;
    for (int sub = 0; sub < nsub; ++sub) {
      bf16x8 bfr[4];
#pragma unroll
      for (int m = 0; m < 4; ++m)
        bfr[m] = *(const bf16x8*)&kbuf[(sub * 16 + lr) * 128 + coff[m]];
      const bool masked = diag && (sub == w);
      float csum = 0.0f;
#pragma unroll
      for (int hh = 0; hh < 2; ++hh) {
        f32x4 acc = {0.f, 0.f, 0.f, 0.f};
#pragma unroll
        for (int m = 0; m < 4; ++m)
          acc = __builtin_amdgcn_mfma_f32_16x16x32_bf16(aq[hh][m], bfr[m], acc, 0, 0, 0);
#pragma unroll
        for (int r = 0; r < 4; ++r) {
          float e = exp2f(__builtin_fmaf(acc[r], SCALING * LOG2E, l2r[hh][r]));
          if (masked && lr > quad * 4 + r) e = 0.0f;
          csum += e;
        }
      }
      csum += __shfl_xor(csum, 16);
      csum += __shfl_xor(csum, 32);
      if (lane < 16) atomicAdd(&colacc[t * 64 + sub * 16 + lr], csum);
    }
    __syncthreads();
    cur ^= 1;
  }
  // batched flush: one global atomic per column this block touched
  for (int c = tid; c < ncol; c += 256) atomicAdd(&imp[c], colacc[c]);
}

// ============================================================
// Kernel 5: exact radix-select of top-1024 + stable index-ordered
// compaction.
// ============================================================
__global__ __launch_bounds__(1024) void topk_kernel(
    const float* __restrict__ imp, const int* __restrict__ ids,
    int* __restrict__ out, int out_size) {
  __shared__ unsigned vals[L_SEQ];      // float bits; imp > 0 so uint order == float order
  __shared__ unsigned hist[256];
  __shared__ unsigned bc[2];
  __shared__ int wsum[16];
  __shared__ int wsum2[16];
  __shared__ int sel[K_SEL + 1];
  const int tid = threadIdx.x;
  const int lane = tid & 63, wv = tid >> 6;

  for (int i = tid; i < L_SEQ; i += 1024) vals[i] = __float_as_uint(imp[i]);
  __syncthreads();

  // ---- byte-wise radix select: exact value T of the K_SEL-th largest ----
  unsigned prefix = 0;
  int remaining = K_SEL;
#pragma unroll 1
  for (int shift = 24; shift >= 0; shift -= 8) {
    if (tid < 256) hist[tid] = 0;
    __syncthreads();
    const unsigned hmask = (shift == 24) ? 0u : (0xFFFFFFFFu << (shift + 8));
    for (int i = tid; i < L_SEQ; i += 1024) {
      const unsigned v = vals[i];
      if ((v & hmask) == prefix) atomicAdd(&hist[(v >> shift) & 255u], 1u);
    }
    __syncthreads();
    if (tid == 0) {
      unsigned cum = 0;
      for (int b = 255; b >= 0; --b) {
        const unsigned h = hist[b];
        if (cum + h >= (unsigned)remaining) { bc[0] = (unsigned)b; bc[1] = cum; break; }
        cum += h;
      }
    }
    __syncthreads();
    prefix |= bc[0] << shift;
    remaining -= (int)bc[1];
    __syncthreads();
  }
  const unsigned T = prefix;
  // select all v > T, plus the `remaining` lowest-index elements with v == T.

  const int i0 = tid * 4;
  const unsigned v0 = vals[i0], v1 = vals[i0 + 1], v2 = vals[i0 + 2], v3 = vals[i0 + 3];
  const int e0 = (v0 == T), e1 = (v1 == T), e2 = (v2 == T), e3 = (v3 == T);
  const int eqc = e0 + e1 + e2 + e3;

  int x = eqc;
#pragma unroll
  for (int d = 1; d < 64; d <<= 1) { const int y = __shfl_up(x, d); if (lane >= d) x += y; }
  if (lane == 63) wsum[wv] = x;
  __syncthreads();
  if (tid < 16) {
    int s = wsum[tid];
#pragma unroll
    for (int d = 1; d < 16; d <<= 1) { const int y = __shfl_up(s, d); if (tid >= d) s += y; }
    wsum[tid] = s;
  }
  __syncthreads();
  const int eq_excl = (wv ? wsum[wv - 1] : 0) + x - eqc;
  const int r0 = eq_excl, r1 = r0 + e0, r2 = r1 + e1, r3 = r2 + e2;
  const int s0 = (v0 > T) || (e0 && r0 < remaining);
  const int s1 = (v1 > T) || (e1 && r1 < remaining);
  const int s2 = (v2 > T) || (e2 && r2 < remaining);
  const int s3 = (v3 > T) || (e3 && r3 < remaining);
  const int selc = s0 + s1 + s2 + s3;

  int x2 = selc;
#pragma unroll
  for (int d = 1; d < 64; d <<= 1) { const int y = __shfl_up(x2, d); if (lane >= d) x2 += y; }
  if (lane == 63) wsum2[wv] = x2;
  __syncthreads();
  if (tid < 16) {
    int s = wsum2[tid];
#pragma unroll
    for (int d = 1; d < 16; d <<= 1) { const int y = __shfl_up(s, d); if (tid >= d) s += y; }
    wsum2[tid] = s;
  }
  __syncthreads();
  int pos = (wv ? wsum2[wv - 1] : 0) + x2 - selc;
  if (s0) sel[pos++] = i0;
  if (s1) sel[pos++] = i0 + 1;
  if (s2) sel[pos++] = i0 + 2;
  if (s3) sel[pos++] = i0 + 3;
  if (tid == 0) sel[K_SEL] = L_SEQ - 1;
  __syncthreads();

  const int half = out_size >> 1;
  for (int i = tid; i < half; i += 1024) {
    const int idx2 = (i < K_SEL) ? sel[i] : sel[K_SEL];
    out[half + i] = idx2;
    out[i] = ids[idx2];
  }
}

// ============================================================
extern "C" void kernel_launch(void* const* d_in, const int* in_sizes, int n_in,
                              void* d_out, int out_size, void* d_ws, size_t ws_size,
                              hipStream_t stream) {
  const int*   ids   = (const int*)d_in[0];
  const float* table = (const float*)d_in[1];
  const float* wq    = (const float*)d_in[2];
  const float* wk    = (const float*)d_in[3];
  char* ws = (char*)d_ws;
  unsigned short* Wt = (unsigned short*)ws;                           // 12 MB [3072][2048]
  unsigned short* C  = (unsigned short*)(ws + 12ull * 1024 * 1024);   // 24 MB [4096][3072]
  float* imp = (float*)(ws + 36ull * 1024 * 1024);                    // 16 KB
  float2* tab = (float2*)(ws + 38ull * 1024 * 1024);                  // 2 MB [4096][64]
  unsigned short* A = (unsigned short*)(ws + 40ull * 1024 * 1024);    // 16 MB [4096][2048]
  int* out = (int*)d_out;

  hipMemsetAsync(imp, 0, L_SEQ * sizeof(float), stream);

  dim3 blk(256);
  rope_tab<<<(L_SEQ * 64) / 256, blk, 0, stream>>>(tab);
  prep_a<<<L_SEQ, blk, 0, stream>>>(ids, table, A);
  prep_w<<<dim3(48, 32), blk, 0, stream>>>(wq, wk, Wt);
  gemm_qk<<<dim3(CSTR / 128, L_SEQ / 128), blk, 0, stream>>>(A, Wt, C);
  rope_all<<<(L_SEQ * 24 * 16) / 256, blk, 0, stream>>>(C, tab);
  attn_fused<<<dim3(64, NKV), blk, 0, stream>>>(C, C + 2048, imp);
  topk_kernel<<<1, 1024, 0, stream>>>(imp, ids, out, out_size);
}

// Round 6
// 585.834 us; speedup vs baseline: 1.2453x; 1.2453x over previous
//
#include <hip/hip_runtime.h>
#include <hip/hip_bf16.h>
#include <math.h>

// ---------------- problem constants ----------------
#define L_SEQ   4096
#define D_MODEL 2048
#define NQ      16
#define NKV     8
#define HD      128
#define CSTR    3072                   // combined QK row stride (NQ*HD + NKV*HD)
#define SCALING 0.08838834764831845f   // 128^-0.5
#define LOG2E   1.4426950408889634f
#define K_SEL   1024                   // L * 0.25
#define CHUNK   8                      // j-tiles per attn block
#define NCHUNK  288                    // sum_{b=0..63} ceil((b+1)/8)

typedef __attribute__((ext_vector_type(8))) short bf16x8;
typedef __attribute__((ext_vector_type(4))) float f32x4;

__device__ __forceinline__ unsigned short f2bf(float f) {
  union { float f; unsigned u; } v; v.f = f;
  unsigned r = v.u + 0x7fffu + ((v.u >> 16) & 1u);   // RNE
  return (unsigned short)(r >> 16);
}
__device__ __forceinline__ unsigned pk2(float a, float b) {
  return (__float_as_uint(b) & 0xffff0000u) | (__float_as_uint(a) >> 16);
}
__device__ __forceinline__ float bf2f(unsigned short b) {
  union { unsigned u; float f; } v; v.u = ((unsigned)b) << 16;
  return v.f;
}

typedef __attribute__((address_space(3))) unsigned int lds_u32;
typedef const __attribute__((address_space(1))) unsigned int glob_u32;
__device__ __forceinline__ void gl2lds16(const unsigned short* g, unsigned short* l) {
  __builtin_amdgcn_global_load_lds((glob_u32*)g, (lds_u32*)l, 16, 0, 0);
}

// ============================================================
// Kernel 1: Wt[3072][2048] bf16 = transpose([wq | wk]), k-contiguous rows.
// ============================================================
__global__ __launch_bounds__(256) void prep_w(
    const float* __restrict__ wq, const float* __restrict__ wk,
    unsigned short* __restrict__ Wt) {
  __shared__ __align__(16) unsigned short T[64][80];
  const int tid = threadIdx.x;
  const int nt = blockIdx.x;      // 48 n-tiles
  const int kt = blockIdx.y;      // 32 k-tiles
  const float* src; int srcN, n0;
  if (nt < 32) { src = wq; srcN = 2048; n0 = nt * 64; }
  else         { src = wk; srcN = 1024; n0 = (nt - 32) * 64; }
  const int k0 = kt * 64;
#pragma unroll
  for (int p = 0; p < 4; ++p) {
    const int idx = p * 256 + tid;
    const int row = idx >> 4;
    const int c4 = (idx & 15) * 4;
    float4 v = *(const float4*)(src + (size_t)(k0 + row) * srcN + n0 + c4);
    T[c4 + 0][row] = f2bf(v.x); T[c4 + 1][row] = f2bf(v.y);
    T[c4 + 2][row] = f2bf(v.z); T[c4 + 3][row] = f2bf(v.w);
  }
  __syncthreads();
#pragma unroll
  for (int p = 0; p < 2; ++p) {
    const int c = p * 256 + tid;
    const int n = c >> 3, k8 = (c & 7) * 8;
    *(uint4*)(Wt + (size_t)(nt * 64 + n) * D_MODEL + k0 + k8) = *(const uint4*)(&T[n][k8]);
  }
}

// ============================================================
// Kernel 1b: A_bf16[4096][2048] = gather(table, ids), pk2-truncated
// (bit-identical to the original in-gemm conversion).
// ============================================================
__global__ __launch_bounds__(256) void prep_a(
    const int* __restrict__ ids, const float* __restrict__ table,
    unsigned short* __restrict__ A) {
  const int row = blockIdx.x;
  const float* src = table + (size_t)ids[row] * D_MODEL;
  const int c = threadIdx.x * 8;
  const float4 f0 = *(const float4*)(src + c);
  const float4 f1 = *(const float4*)(src + c + 4);
  uint4 u;
  u.x = pk2(f0.x, f0.y); u.y = pk2(f0.z, f0.w);
  u.z = pk2(f1.x, f1.y); u.w = pk2(f1.z, f1.w);
  *(uint4*)(A + (size_t)row * D_MODEL + c) = u;
}

// ============================================================
// Kernel 2: C[4096][3072] = A_bf16 @ [wq|wk]^T, MFMA bf16.
// Double-buffered 2-phase pipeline: stage(next tile) is issued BEFORE
// compute(cur), one barrier per K-step drains it after the MFMAs.
// Both operands staged via global_load_lds (16B), XOR chunk source
// swizzle matched on the read side (verified bit-exact in round 5).
// ============================================================
__global__ __launch_bounds__(256) void gemm_qk(
    const unsigned short* __restrict__ A,
    const unsigned short* __restrict__ Wt, unsigned short* __restrict__ C) {
  __shared__ __align__(16) unsigned short As[2][128 * 32];
  __shared__ __align__(16) unsigned short Bs[2][128 * 32];
  const int tid = threadIdx.x;
  const int w = tid >> 6, lane = tid & 63;
  const int quad = lane >> 4, lr = lane & 15;
  const int m0 = blockIdx.y * 128, n0 = blockIdx.x * 128;
  const int wm = (w >> 1) * 64, wn = (w & 1) * 64;

  // staging: lane covers row (lane>>2), source chunk (lane&3)^((lane>>3)&3)
  const int srw = lane >> 2;
  const int schk = ((lane & 3) ^ ((lane >> 3) & 3)) * 8;
  const unsigned short* aptr0 = A + (size_t)(m0 + w * 16 + srw) * D_MODEL + schk;
  const unsigned short* aptr1 = aptr0 + (size_t)64 * D_MODEL;
  const unsigned short* bptr0 = Wt + (size_t)(n0 + w * 16 + srw) * D_MODEL + schk;
  const unsigned short* bptr1 = bptr0 + (size_t)64 * D_MODEL;
  const int sloff0 = (w * 16) * 32;
  const int sloff1 = (64 + w * 16) * 32;

  // read-side swizzle selector: (row>>1)&3 == (lr>>1)&3 for our rows
  const int rsw = ((lr >> 1) & 3);

  f32x4 acc[4][4];
#pragma unroll
  for (int i = 0; i < 4; ++i)
#pragma unroll
    for (int j = 0; j < 4; ++j) acc[i][j] = (f32x4){0.f, 0.f, 0.f, 0.f};

  // prologue: stage k0=0 into buffer 0
  gl2lds16(aptr0, &As[0][sloff0]);
  gl2lds16(aptr1, &As[0][sloff1]);
  gl2lds16(bptr0, &Bs[0][sloff0]);
  gl2lds16(bptr1, &Bs[0][sloff1]);
  __syncthreads();
  int cur = 0;
  for (int k0 = 0; k0 < D_MODEL; k0 += 32) {
    if (k0 + 32 < D_MODEL) {
      const int nb = cur ^ 1;
      gl2lds16(aptr0 + k0 + 32, &As[nb][sloff0]);
      gl2lds16(aptr1 + k0 + 32, &As[nb][sloff1]);
      gl2lds16(bptr0 + k0 + 32, &Bs[nb][sloff0]);
      gl2lds16(bptr1 + k0 + 32, &Bs[nb][sloff1]);
    }
    bf16x8 af[4], bfr[4];
#pragma unroll
    for (int mt = 0; mt < 4; ++mt)
      af[mt] = *(const bf16x8*)&As[cur][(wm + mt * 16 + lr) * 32 + (quad ^ rsw) * 8];
#pragma unroll
    for (int nt = 0; nt < 4; ++nt)
      bfr[nt] = *(const bf16x8*)&Bs[cur][(wn + nt * 16 + lr) * 32 + (quad ^ rsw) * 8];
#pragma unroll
    for (int mt = 0; mt < 4; ++mt)
#pragma unroll
      for (int nt = 0; nt < 4; ++nt)
        acc[mt][nt] = __builtin_amdgcn_mfma_f32_16x16x32_bf16(af[mt], bfr[nt], acc[mt][nt], 0, 0, 0);
    __syncthreads();
    cur ^= 1;
  }
#pragma unroll
  for (int mt = 0; mt < 4; ++mt) {
    const int row = m0 + wm + mt * 16 + quad * 4;
#pragma unroll
    for (int nt = 0; nt < 4; ++nt) {
      const int col = n0 + wn + nt * 16 + lr;
#pragma unroll
      for (int r = 0; r < 4; ++r)
        C[(size_t)(row + r) * CSTR + col] = f2bf(acc[mt][nt][r]);
    }
  }
}

// ============================================================
// Kernel 3a: RoPE cos/sin table tab[4096][64] (constants only).
// ============================================================
__global__ __launch_bounds__(256) void rope_tab(float2* __restrict__ tab) {
  const int g = blockIdx.x * blockDim.x + threadIdx.x;   // 4096*64
  const int t = g & 63;
  const int i = g >> 6;
  const float invf = exp2f((float)t * (-13.287712379549449f / 64.0f));
  const float ang = (float)i * invf;
  tab[g] = make_float2(cosf(ang), sinf(ang));
}

// ============================================================
// Kernel 3b: RoPE in place on combined C[4096][3072], table-driven.
// ============================================================
__global__ __launch_bounds__(256) void rope_all(
    unsigned short* __restrict__ C, const float2* __restrict__ tab) {
  const int g = blockIdx.x * blockDim.x + threadIdx.x;   // L*24*16 threads
  const int t4 = (g & 15) * 4;
  const int hi = g >> 4;
  const int h = hi % 24;
  const int i = hi / 24;
  const size_t base = (size_t)i * CSTR + h * HD + t4;
  ushort4 a = *(const ushort4*)(C + base);
  ushort4 b = *(const ushort4*)(C + base + 64);
  const float2 cs0 = tab[i * 64 + t4 + 0];
  const float2 cs1 = tab[i * 64 + t4 + 1];
  const float2 cs2 = tab[i * 64 + t4 + 2];
  const float2 cs3 = tab[i * 64 + t4 + 3];
  const float a0 = bf2f(a.x), a1 = bf2f(a.y), a2 = bf2f(a.z), a3 = bf2f(a.w);
  const float b0 = bf2f(b.x), b1 = bf2f(b.y), b2 = bf2f(b.z), b3 = bf2f(b.w);
  ushort4 ra, rb;
  ra.x = f2bf(a0 * cs0.x - b0 * cs0.y); rb.x = f2bf(b0 * cs0.x + a0 * cs0.y);
  ra.y = f2bf(a1 * cs1.x - b1 * cs1.y); rb.y = f2bf(b1 * cs1.x + a1 * cs1.y);
  ra.z = f2bf(a2 * cs2.x - b2 * cs2.y); rb.z = f2bf(b2 * cs2.x + a2 * cs2.y);
  ra.w = f2bf(a3 * cs3.x - b3 * cs3.y); rb.w = f2bf(b3 * cs3.x + a3 * cs3.y);
  *(ushort4*)(C + base) = ra;
  *(ushort4*)(C + base + 64) = rb;
}

// ============================================================
// Shared mapping: blockIdx.x (0..NCHUNK-1) -> (bx, chunk), heavy bx first.
// ============================================================
__device__ __forceinline__ void chunk_map(int bidx, int& bx, int& ch) {
  int rem = bidx;
  for (int b = 63; b >= 0; --b) {
    const int nc = (b + 2 + CHUNK - 1) >> 3;   // ceil((b+1)/8)
    if (rem < nc) { bx = b; ch = rem; return; }
    rem -= nc;
  }
  bx = 0; ch = 0;
}

// ------------------------------------------------------------
// K-tile staging: 64x128 bf16, linear LDS [64][128], XOR-swizzled SOURCE
// (16B chunk index ^= row&7).  global_load_lds: uniform LDS base + lane*16.
// ------------------------------------------------------------
__device__ __forceinline__ void stage_k(
    const unsigned short* __restrict__ kb_lane,   // per-lane pre-swizzled base
    unsigned short* buf, int j0, int w) {
#pragma unroll
  for (int p = 0; p < 4; ++p)
    gl2lds16(kb_lane + (size_t)(j0 + p * 16) * CSTR, &buf[(p * 16 + w * 4) * 128]);
}

// ============================================================
// Kernel 4a: row-denominator partials. Block = (chunk of <=8 j-tiles, kvh).
// 2-phase double-buffered K staging; atomicAdd partials into Z[16][4096].
// ============================================================
__global__ __launch_bounds__(256) void attn_z(
    const unsigned short* __restrict__ Qb,  // [L][CSTR], q heads at col 0
    const unsigned short* __restrict__ Kb,  // = Qb + 2048
    float* __restrict__ Z) {
  __shared__ __align__(16) unsigned short Ks[2][64 * 128];
  const int tid = threadIdx.x;
  const int w = tid >> 6, lane = tid & 63;
  const int quad = lane >> 4, lr = lane & 15;
  const int kvh = blockIdx.y;
  int bx, ch; chunk_map(blockIdx.x, bx, ch);
  const int q0 = bx * 64;
  const int t0 = ch * CHUNK;
  const int t1 = min(t0 + CHUNK, bx + 1);

  const int srow = w * 4 + (lane >> 4);
  const int scol = (lane & 15) ^ (srow & 7);
  const unsigned short* kb_lane = Kb + (size_t)srow * CSTR + kvh * HD + scol * 8;

  int coff[4];
#pragma unroll
  for (int m = 0; m < 4; ++m) coff[m] = (((m * 4 + quad) ^ (lr & 7)) * 8);

  bf16x8 aq[2][4];
  const size_t rowb = (size_t)(q0 + w * 16 + lr) * CSTR;
#pragma unroll
  for (int hh = 0; hh < 2; ++hh)
#pragma unroll
    for (int m = 0; m < 4; ++m)
      aq[hh][m] = *(const bf16x8*)(Qb + rowb + (2 * kvh + hh) * HD + m * 32 + quad * 8);

  float zp[2][4] = {};

  stage_k(kb_lane, Ks[0], t0 * 64, w);
  __syncthreads();
  int cur = 0;
  for (int t = t0; t < t1; ++t) {
    if (t + 1 < t1) stage_k(kb_lane, Ks[cur ^ 1], (t + 1) * 64, w);
    const unsigned short* kbuf = Ks[cur];
    const bool diag = (t == bx);
    const int nsub = diag ? (w + 1) : 4;
    for (int sub = 0; sub < nsub; ++sub) {
      bf16x8 bfr[4];
#pragma unroll
      for (int m = 0; m < 4; ++m)
        bfr[m] = *(const bf16x8*)&kbuf[(sub * 16 + lr) * 128 + coff[m]];
      const bool masked = diag && (sub == w);
#pragma unroll
      for (int hh = 0; hh < 2; ++hh) {
        f32x4 acc = {0.f, 0.f, 0.f, 0.f};
#pragma unroll
        for (int m = 0; m < 4; ++m)
          acc = __builtin_amdgcn_mfma_f32_16x16x32_bf16(aq[hh][m], bfr[m], acc, 0, 0, 0);
#pragma unroll
        for (int r = 0; r < 4; ++r) {
          float e = exp2f(acc[r] * (SCALING * LOG2E));
          if (masked && lr > quad * 4 + r) e = 0.0f;
          zp[hh][r] += e;
        }
      }
    }
    __syncthreads();
    cur ^= 1;
  }
#pragma unroll
  for (int hh = 0; hh < 2; ++hh)
#pragma unroll
    for (int r = 0; r < 4; ++r) {
      float z = zp[hh][r];
      z += __shfl_xor(z, 1); z += __shfl_xor(z, 2);
      z += __shfl_xor(z, 4); z += __shfl_xor(z, 8);
      if (lr == 0)
        atomicAdd(&Z[(size_t)(2 * kvh + hh) * L_SEQ + q0 + w * 16 + quad * 4 + r], z);
    }
}

// ============================================================
// Kernel 4b: column sums. LDS column accumulator in the loop; single
// batched global-atomic flush at block end.
// ============================================================
__global__ __launch_bounds__(256) void attn_col(
    const unsigned short* __restrict__ Qb,
    const unsigned short* __restrict__ Kb,
    const float* __restrict__ Z, float* __restrict__ imp) {
  __shared__ __align__(16) unsigned short Ks[2][64 * 128];
  __shared__ float colacc[CHUNK * 64];
  const int tid = threadIdx.x;
  const int w = tid >> 6, lane = tid & 63;
  const int quad = lane >> 4, lr = lane & 15;
  const int kvh = blockIdx.y;
  int bx, ch; chunk_map(blockIdx.x, bx, ch);
  const int q0 = bx * 64;
  const int t0 = ch * CHUNK;
  const int t1 = min(t0 + CHUNK, bx + 1);

  const int srow = w * 4 + (lane >> 4);
  const int scol = (lane & 15) ^ (srow & 7);
  const unsigned short* kb_lane = Kb + (size_t)srow * CSTR + kvh * HD + scol * 8;

  int coff[4];
#pragma unroll
  for (int m = 0; m < 4; ++m) coff[m] = (((m * 4 + quad) ^ (lr & 7)) * 8);

  bf16x8 aq[2][4];
  const size_t rowb = (size_t)(q0 + w * 16 + lr) * CSTR;
#pragma unroll
  for (int hh = 0; hh < 2; ++hh)
#pragma unroll
    for (int m = 0; m < 4; ++m)
      aq[hh][m] = *(const bf16x8*)(Qb + rowb + (2 * kvh + hh) * HD + m * 32 + quad * 8);

  float l2r[2][4];
#pragma unroll
  for (int hh = 0; hh < 2; ++hh) {
    const float4 z4 = *(const float4*)&Z[(size_t)(2 * kvh + hh) * L_SEQ + q0 + w * 16 + quad * 4];
    l2r[hh][0] = -__log2f(z4.x); l2r[hh][1] = -__log2f(z4.y);
    l2r[hh][2] = -__log2f(z4.z); l2r[hh][3] = -__log2f(z4.w);
  }

  stage_k(kb_lane, Ks[0], t0 * 64, w);
  for (int c = tid; c < CHUNK * 64; c += 256) colacc[c] = 0.0f;
  __syncthreads();
  int cur = 0;
  for (int t = t0; t < t1; ++t) {
    if (t + 1 < t1) stage_k(kb_lane, Ks[cur ^ 1], (t + 1) * 64, w);
    const unsigned short* kbuf = Ks[cur];
    const bool diag = (t == bx);
    const int nsub = diag ? (w + 1) : 4;
    for (int sub = 0; sub < nsub; ++sub) {
      bf16x8 bfr[4];
#pragma unroll
      for (int m = 0; m < 4; ++m)
        bfr[m] = *(const bf16x8*)&kbuf[(sub * 16 + lr) * 128 + coff[m]];
      const bool masked = diag && (sub == w);
      float csum = 0.0f;
#pragma unroll
      for (int hh = 0; hh < 2; ++hh) {
        f32x4 acc = {0.f, 0.f, 0.f, 0.f};
#pragma unroll
        for (int m = 0; m < 4; ++m)
          acc = __builtin_amdgcn_mfma_f32_16x16x32_bf16(aq[hh][m], bfr[m], acc, 0, 0, 0);
#pragma unroll
        for (int r = 0; r < 4; ++r) {
          float e = exp2f(__builtin_fmaf(acc[r], SCALING * LOG2E, l2r[hh][r]));
          if (masked && lr > quad * 4 + r) e = 0.0f;
          csum += e;
        }
      }
      csum += __shfl_xor(csum, 16);
      csum += __shfl_xor(csum, 32);
      if (lane < 16) atomicAdd(&colacc[(t - t0) * 64 + sub * 16 + lr], csum);
    }
    __syncthreads();
    cur ^= 1;
  }
  // batched flush: one global atomic per column this block touched
  const int ncol = (t1 - t0) * 64;
  const int jb = t0 * 64;
  for (int c = tid; c < ncol; c += 256) atomicAdd(&imp[jb + c], colacc[c]);
}

// ============================================================
// Kernel 5: exact radix-select of top-1024 + stable index-ordered
// compaction.
// ============================================================
__global__ __launch_bounds__(1024) void topk_kernel(
    const float* __restrict__ imp, const int* __restrict__ ids,
    int* __restrict__ out, int out_size) {
  __shared__ unsigned vals[L_SEQ];      // float bits; imp > 0 so uint order == float order
  __shared__ unsigned hist[256];
  __shared__ unsigned bc[2];
  __shared__ int wsum[16];
  __shared__ int wsum2[16];
  __shared__ int sel[K_SEL + 1];
  const int tid = threadIdx.x;
  const int lane = tid & 63, wv = tid >> 6;

  for (int i = tid; i < L_SEQ; i += 1024) vals[i] = __float_as_uint(imp[i]);
  __syncthreads();

  // ---- byte-wise radix select: exact value T of the K_SEL-th largest ----
  unsigned prefix = 0;
  int remaining = K_SEL;
#pragma unroll 1
  for (int shift = 24; shift >= 0; shift -= 8) {
    if (tid < 256) hist[tid] = 0;
    __syncthreads();
    const unsigned hmask = (shift == 24) ? 0u : (0xFFFFFFFFu << (shift + 8));
    for (int i = tid; i < L_SEQ; i += 1024) {
      const unsigned v = vals[i];
      if ((v & hmask) == prefix) atomicAdd(&hist[(v >> shift) & 255u], 1u);
    }
    __syncthreads();
    if (tid == 0) {
      unsigned cum = 0;
      for (int b = 255; b >= 0; --b) {
        const unsigned h = hist[b];
        if (cum + h >= (unsigned)remaining) { bc[0] = (unsigned)b; bc[1] = cum; break; }
        cum += h;
      }
    }
    __syncthreads();
    prefix |= bc[0] << shift;
    remaining -= (int)bc[1];
    __syncthreads();
  }
  const unsigned T = prefix;
  // select all v > T, plus the `remaining` lowest-index elements with v == T.

  const int i0 = tid * 4;
  const unsigned v0 = vals[i0], v1 = vals[i0 + 1], v2 = vals[i0 + 2], v3 = vals[i0 + 3];
  const int e0 = (v0 == T), e1 = (v1 == T), e2 = (v2 == T), e3 = (v3 == T);
  const int eqc = e0 + e1 + e2 + e3;

  int x = eqc;
#pragma unroll
  for (int d = 1; d < 64; d <<= 1) { const int y = __shfl_up(x, d); if (lane >= d) x += y; }
  if (lane == 63) wsum[wv] = x;
  __syncthreads();
  if (tid < 16) {
    int s = wsum[tid];
#pragma unroll
    for (int d = 1; d < 16; d <<= 1) { const int y = __shfl_up(s, d); if (tid >= d) s += y; }
    wsum[tid] = s;
  }
  __syncthreads();
  const int eq_excl = (wv ? wsum[wv - 1] : 0) + x - eqc;
  const int r0 = eq_excl, r1 = r0 + e0, r2 = r1 + e1, r3 = r2 + e2;
  const int s0 = (v0 > T) || (e0 && r0 < remaining);
  const int s1 = (v1 > T) || (e1 && r1 < remaining);
  const int s2 = (v2 > T) || (e2 && r2 < remaining);
  const int s3 = (v3 > T) || (e3 && r3 < remaining);
  const int selc = s0 + s1 + s2 + s3;

  int x2 = selc;
#pragma unroll
  for (int d = 1; d < 64; d <<= 1) { const int y = __shfl_up(x2, d); if (lane >= d) x2 += y; }
  if (lane == 63) wsum2[wv] = x2;
  __syncthreads();
  if (tid < 16) {
    int s = wsum2[tid];
#pragma unroll
    for (int d = 1; d < 16; d <<= 1) { const int y = __shfl_up(s, d); if (tid >= d) s += y; }
    wsum2[tid] = s;
  }
  __syncthreads();
  int pos = (wv ? wsum2[wv - 1] : 0) + x2 - selc;
  if (s0) sel[pos++] = i0;
  if (s1) sel[pos++] = i0 + 1;
  if (s2) sel[pos++] = i0 + 2;
  if (s3) sel[pos++] = i0 + 3;
  if (tid == 0) sel[K_SEL] = L_SEQ - 1;
  __syncthreads();

  const int half = out_size >> 1;
  for (int i = tid; i < half; i += 1024) {
    const int idx2 = (i < K_SEL) ? sel[i] : sel[K_SEL];
    out[half + i] = idx2;
    out[i] = ids[idx2];
  }
}

// ============================================================
extern "C" void kernel_launch(void* const* d_in, const int* in_sizes, int n_in,
                              void* d_out, int out_size, void* d_ws, size_t ws_size,
                              hipStream_t stream) {
  const int*   ids   = (const int*)d_in[0];
  const float* table = (const float*)d_in[1];
  const float* wq    = (const float*)d_in[2];
  const float* wk    = (const float*)d_in[3];
  char* ws = (char*)d_ws;
  unsigned short* Wt = (unsigned short*)ws;                           // 12 MB [3072][2048]
  unsigned short* C  = (unsigned short*)(ws + 12ull * 1024 * 1024);   // 24 MB [4096][3072]
  float* imp = (float*)(ws + 36ull * 1024 * 1024);                    // 16 KB
  float* Z   = (float*)(ws + 36ull * 1024 * 1024 + 16384);            // 256 KB [16][4096]
  float2* tab = (float2*)(ws + 38ull * 1024 * 1024);                  // 2 MB [4096][64]
  unsigned short* A = (unsigned short*)(ws + 40ull * 1024 * 1024);    // 16 MB [4096][2048]
  int* out = (int*)d_out;

  hipMemsetAsync(imp, 0, L_SEQ * sizeof(float), stream);
  hipMemsetAsync(Z, 0, NQ * L_SEQ * sizeof(float), stream);

  dim3 blk(256);
  rope_tab<<<(L_SEQ * 64) / 256, blk, 0, stream>>>(tab);
  prep_a<<<L_SEQ, blk, 0, stream>>>(ids, table, A);
  prep_w<<<dim3(48, 32), blk, 0, stream>>>(wq, wk, Wt);
  gemm_qk<<<dim3(CSTR / 128, L_SEQ / 128), blk, 0, stream>>>(A, Wt, C);
  rope_all<<<(L_SEQ * 24 * 16) / 256, blk, 0, stream>>>(C, tab);
  attn_z<<<dim3(NCHUNK, NKV), blk, 0, stream>>>(C, C + 2048, Z);
  attn_col<<<dim3(NCHUNK, NKV), blk, 0, stream>>>(C, C + 2048, Z, imp);
  topk_kernel<<<1, 1024, 0, stream>>>(imp, ids, out, out_size);
}